// Round 6
// baseline (173.679 us; speedup 1.0000x reference)
//
#include <hip/hip_runtime.h>
#include <hip/hip_bf16.h>

// ContrastiveLoss (NT-Xent): B=2048, D=256, T=0.5
// loss = mean_i [ -2*dot(zh_i, zh_pos(i)) + log( sum_j exp(2*dot(zh_i, zh_j)) - e^2 ) ]
// Two kernels (coop launch breaks graph capture -- learned R5):
//  k_norm: normalize pairs -> zb (bf16), zb2 (bf16*2log2e), pos-dots pd; zero S/cnt
//  k_sim:  1056 x 128x64 upper-triangular half-tiles, atomics into S;
//          last block (device-scope counter) computes the final loss -> out.

typedef __attribute__((ext_vector_type(8))) short short8;
typedef __attribute__((ext_vector_type(4))) float float4v;

#define NROWS 4096
#define DIM 256
#define NB 2048
#define TEMP_INV 2.0f
#define SCALE 2.8853900817779268f  // 2*log2(e)
// 280 shorts = 140 dwords stride; each lane's b128 span tiles the 32 banks at
// exactly 2 lanes/bank = conflict floor (2-way free, m136).
#define LDS_STRIDE 280
#define NTILES 528        // 32*33/2 triangular 128x128 tiles
#define NBLOCKS (2*NTILES) // one block per 128x64 half-tile

static __device__ __forceinline__ unsigned short f2bf_rne(float f) {
    unsigned int x = __float_as_uint(f);
    unsigned int r = x + 0x7FFFu + ((x >> 16) & 1u);
    return (unsigned short)(r >> 16);
}

// K1: normalize pair (p, p+NB); zb, zb2 (pre-scaled), pd; zero S and cnt.
__global__ __launch_bounds__(256) void k_norm(const float* __restrict__ zi,
                                              const float* __restrict__ zj,
                                              unsigned short* __restrict__ zb,
                                              unsigned short* __restrict__ zb2,
                                              float* __restrict__ pd,
                                              float* __restrict__ S,
                                              unsigned int* __restrict__ cnt) {
    if (blockIdx.x == 0 && threadIdx.x == 0) *cnt = 0u;
    if (threadIdx.x < 8) S[blockIdx.x * 8 + threadIdx.x] = 0.0f;
    int wave = threadIdx.x >> 6, lane = threadIdx.x & 63;
    int p = blockIdx.x * 4 + wave;  // pair index: rows p and p+NB
    float4 vi = *(const float4*)(zi + (size_t)p * DIM + lane * 4);
    float4 vj = *(const float4*)(zj + (size_t)p * DIM + lane * 4);
    float ssi = vi.x * vi.x + vi.y * vi.y + vi.z * vi.z + vi.w * vi.w;
    float ssj = vj.x * vj.x + vj.y * vj.y + vj.z * vj.z + vj.w * vj.w;
    float dij = vi.x * vj.x + vi.y * vj.y + vi.z * vj.z + vi.w * vj.w;
    #pragma unroll
    for (int off = 32; off > 0; off >>= 1) {
        ssi += __shfl_xor(ssi, off);
        ssj += __shfl_xor(ssj, off);
        dij += __shfl_xor(dij, off);
    }
    float si = 1.0f / fmaxf(sqrtf(ssi), 1e-12f);
    float sj = 1.0f / fmaxf(sqrtf(ssj), 1e-12f);
    ushort4 a, b;
    a.x = f2bf_rne(vi.x * si); a.y = f2bf_rne(vi.y * si);
    a.z = f2bf_rne(vi.z * si); a.w = f2bf_rne(vi.w * si);
    b.x = f2bf_rne(vj.x * sj); b.y = f2bf_rne(vj.y * sj);
    b.z = f2bf_rne(vj.z * sj); b.w = f2bf_rne(vj.w * sj);
    *(ushort4*)(zb + (size_t)p * DIM + lane * 4) = a;
    *(ushort4*)(zb + (size_t)(p + NB) * DIM + lane * 4) = b;
    float ki = si * SCALE, kj = sj * SCALE;
    ushort4 a2, b2;
    a2.x = f2bf_rne(vi.x * ki); a2.y = f2bf_rne(vi.y * ki);
    a2.z = f2bf_rne(vi.z * ki); a2.w = f2bf_rne(vi.w * ki);
    b2.x = f2bf_rne(vj.x * kj); b2.y = f2bf_rne(vj.y * kj);
    b2.z = f2bf_rne(vj.z * kj); b2.w = f2bf_rne(vj.w * kj);
    *(ushort4*)(zb2 + (size_t)p * DIM + lane * 4) = a2;
    *(ushort4*)(zb2 + (size_t)(p + NB) * DIM + lane * 4) = b2;
    if (lane == 0) pd[p] = dij * si * sj;
}

// K2: 128x64 half-tiles of the upper triangle. Block = 4 waves; wave owns 32
// i-rows (two reg-resident 16x16 A-tiles from zb2); 64 B-rows in LDS.
// Row sums always; col sums when jb > ib. Last block computes the loss.
__global__ __launch_bounds__(256, 4) void k_sim(const unsigned short* __restrict__ zb,
                                                const unsigned short* __restrict__ zb2,
                                                float* __restrict__ S,
                                                const float* __restrict__ pd,
                                                unsigned int* __restrict__ cnt,
                                                float* __restrict__ out) {
    __shared__ __attribute__((aligned(16))) short Bs[64 * LDS_STRIDE];
    __shared__ float cs[64];
    __shared__ float red[4];
    __shared__ unsigned int lastflag;

    // decode: half-tile id -> (ib, jb, strip)
    int t = blockIdx.x >> 1, strip = blockIdx.x & 1;
    int rem = t, ib = 0;
    while (rem >= 32 - ib) { rem -= 32 - ib; ib++; }
    int jb = ib + rem;
    bool do_col = (jb > ib);

    int tid = threadIdx.x, wave = tid >> 6, lane = tid & 63;
    int m = lane & 15, q = lane >> 4;
    const short* zsB = (const short*)zb;
    const short* zsA = (const short*)zb2;
    int ibase = ib * 128 + wave * 32;
    int j0 = jb * 128 + strip * 64;

    if (tid < 64) cs[tid] = 0.0f;

    // stage 64 B-rows x 256 bf16 into LDS (16B chunks, 8 per thread)
    #pragma unroll
    for (int c = 0; c < 8; c++) {
        int chunk = c * 256 + tid;
        int r = chunk >> 5, cc = chunk & 31;
        *(short8*)(&Bs[r * LDS_STRIDE + cc * 8]) =
            *(const short8*)(zsB + (size_t)(j0 + r) * DIM + cc * 8);
    }

    // A fragments: A[m][k], m = lane&15, k = q*8 + kk (verified 16x16x32 layout)
    short8 A[2][8];
    #pragma unroll
    for (int tt = 0; tt < 2; tt++) {
        const short* arow = zsA + (size_t)(ibase + tt * 16 + m) * DIM + q * 8;
        #pragma unroll
        for (int kk = 0; kk < 8; kk++) A[tt][kk] = *(const short8*)(arow + kk * 32);
    }
    __syncthreads();

    float rowacc[2][4] = {{0.f, 0.f, 0.f, 0.f}, {0.f, 0.f, 0.f, 0.f}};
    #pragma unroll
    for (int jt = 0; jt < 4; jt++) {
        const short* brow = &Bs[(jt * 16 + m) * LDS_STRIDE + q * 8];
        float4v c0 = {0.f, 0.f, 0.f, 0.f};
        float4v c1 = {0.f, 0.f, 0.f, 0.f};
        #pragma unroll
        for (int kk = 0; kk < 8; kk++) {
            short8 b = *(const short8*)(brow + kk * 32);
            c0 = __builtin_amdgcn_mfma_f32_16x16x32_bf16(A[0][kk], b, c0, 0, 0, 0);
            c1 = __builtin_amdgcn_mfma_f32_16x16x32_bf16(A[1][kk], b, c1, 0, 0, 0);
        }
        float csum = 0.0f;
        #pragma unroll
        for (int r = 0; r < 4; r++) {
            float e0 = __builtin_exp2f(c0[r]);
            float e1 = __builtin_exp2f(c1[r]);
            rowacc[0][r] += e0; rowacc[1][r] += e1;
            csum += e0 + e1;
        }
        if (do_col) {
            csum += __shfl_xor(csum, 16);
            csum += __shfl_xor(csum, 32);
            if (lane < 16) atomicAdd(&cs[jt * 16 + m], csum);
        }
    }

    // row sums -> S
    #pragma unroll
    for (int tt = 0; tt < 2; tt++) {
        #pragma unroll
        for (int r = 0; r < 4; r++) {
            float s = rowacc[tt][r];
            s += __shfl_xor(s, 1);
            s += __shfl_xor(s, 2);
            s += __shfl_xor(s, 4);
            s += __shfl_xor(s, 8);
            if (m == 0) atomicAdd(&S[ibase + tt * 16 + q * 4 + r], s);
        }
    }
    if (do_col) {
        __syncthreads();
        if (tid < 64) atomicAdd(&S[j0 + tid], cs[tid]);
    }

    // ---- last-block loss reduction (device-scope counter handshake)
    __threadfence();
    if (tid == 0) {
        unsigned int old = __hip_atomic_fetch_add(cnt, 1u, __ATOMIC_ACQ_REL,
                                                  __HIP_MEMORY_SCOPE_AGENT);
        lastflag = (old == NBLOCKS - 1) ? 1u : 0u;
    }
    __syncthreads();
    if (lastflag) {
        const float E2 = 7.38905609893065f;  // exp(sim_ii) = e^2
        float acc = 0.0f;
        #pragma unroll
        for (int k = 0; k < 16; k++) {
            int i = k * 256 + tid;
            float s = __hip_atomic_load(&S[i], __ATOMIC_RELAXED,
                                        __HIP_MEMORY_SCOPE_AGENT);
            acc += logf(s - E2) - TEMP_INV * pd[i & (NB - 1)];
        }
        #pragma unroll
        for (int off = 32; off > 0; off >>= 1) acc += __shfl_xor(acc, off);
        if (lane == 0) red[wave] = acc;
        __syncthreads();
        if (tid == 0)
            *out = (red[0] + red[1] + red[2] + red[3]) * (1.0f / NROWS);
    }
}

extern "C" void kernel_launch(void* const* d_in, const int* in_sizes, int n_in,
                              void* d_out, int out_size, void* d_ws, size_t ws_size,
                              hipStream_t stream) {
    const float* zi = (const float*)d_in[0];
    const float* zj = (const float*)d_in[1];
    float* out = (float*)d_out;
    char* ws = (char*)d_ws;
    unsigned short* zb  = (unsigned short*)ws;                        // 2 MB bf16 normalized
    unsigned short* zb2 = (unsigned short*)(ws + 2 * 1024 * 1024);    // 2 MB bf16 * 2log2e
    float* S  = (float*)(ws + 4 * 1024 * 1024);                       // 16 KB row exp sums
    float* pd = (float*)(ws + 4 * 1024 * 1024 + 16 * 1024);           // 8 KB pos dots
    unsigned int* cnt = (unsigned int*)(ws + 4 * 1024 * 1024 + 32 * 1024);

    hipLaunchKernelGGL(k_norm, dim3(512), dim3(256), 0, stream,
                       zi, zj, zb, zb2, pd, S, cnt);
    hipLaunchKernelGGL(k_sim, dim3(NBLOCKS), dim3(256), 0, stream,
                       zb, zb2, S, pd, cnt, out);
}

// Round 7
// 79.412 us; speedup vs baseline: 2.1871x; 2.1871x over previous
//
#include <hip/hip_runtime.h>
#include <hip/hip_bf16.h>

// ContrastiveLoss (NT-Xent): B=2048, D=256, T=0.5
// loss = mean_i [ -2*dot(zh_i, zh_pos(i)) + log( sum_j exp(2*dot(zh_i, zh_j)) - e^2 ) ]
// k_norm: normalize pairs -> zb (bf16), zb2 (bf16*2log2e), pos-dots pd; zero out.
// k_sim:  528 upper-triangular 128x128 exp2-tiles; NO global atomics -- each
//         tile's row/col sums go to unique slots of P[32][4096] (plain stores).
// k_loss: S[i] = sum_p P[p][i]; loss reduce.
// R6 lesson: no __launch_bounds__ second arg on k_sim (VGPR=60 spilled A frags
// -> 118us). A[2][8] short8 (64 VGPR) must stay register-resident.

typedef __attribute__((ext_vector_type(8))) short short8;
typedef __attribute__((ext_vector_type(4))) float float4v;

#define NROWS 4096
#define DIM 256
#define NB 2048
#define TEMP_INV 2.0f
#define SCALE 2.8853900817779268f  // 2*log2(e)
// 280 shorts = 140 dwords stride; each lane's b128 span tiles the 32 banks at
// exactly 2 lanes/bank = conflict floor (2-way free, m136).
#define LDS_STRIDE 280
#define NTILES 528  // 32*33/2 triangular 128x128 tiles

static __device__ __forceinline__ unsigned short f2bf_rne(float f) {
    unsigned int x = __float_as_uint(f);
    unsigned int r = x + 0x7FFFu + ((x >> 16) & 1u);
    return (unsigned short)(r >> 16);
}

// K1: normalize pair (p, p+NB); zb, zb2 (pre-scaled), pd; zero out.
__global__ __launch_bounds__(256) void k_norm(const float* __restrict__ zi,
                                              const float* __restrict__ zj,
                                              unsigned short* __restrict__ zb,
                                              unsigned short* __restrict__ zb2,
                                              float* __restrict__ pd,
                                              float* __restrict__ out) {
    if (blockIdx.x == 0 && threadIdx.x == 0) *out = 0.0f;
    int wave = threadIdx.x >> 6, lane = threadIdx.x & 63;
    int p = blockIdx.x * 4 + wave;  // pair index: rows p and p+NB
    float4 vi = *(const float4*)(zi + (size_t)p * DIM + lane * 4);
    float4 vj = *(const float4*)(zj + (size_t)p * DIM + lane * 4);
    float ssi = vi.x * vi.x + vi.y * vi.y + vi.z * vi.z + vi.w * vi.w;
    float ssj = vj.x * vj.x + vj.y * vj.y + vj.z * vj.z + vj.w * vj.w;
    float dij = vi.x * vj.x + vi.y * vj.y + vi.z * vj.z + vi.w * vj.w;
    #pragma unroll
    for (int off = 32; off > 0; off >>= 1) {
        ssi += __shfl_xor(ssi, off);
        ssj += __shfl_xor(ssj, off);
        dij += __shfl_xor(dij, off);
    }
    float si = 1.0f / fmaxf(sqrtf(ssi), 1e-12f);
    float sj = 1.0f / fmaxf(sqrtf(ssj), 1e-12f);
    ushort4 a, b;
    a.x = f2bf_rne(vi.x * si); a.y = f2bf_rne(vi.y * si);
    a.z = f2bf_rne(vi.z * si); a.w = f2bf_rne(vi.w * si);
    b.x = f2bf_rne(vj.x * sj); b.y = f2bf_rne(vj.y * sj);
    b.z = f2bf_rne(vj.z * sj); b.w = f2bf_rne(vj.w * sj);
    *(ushort4*)(zb + (size_t)p * DIM + lane * 4) = a;
    *(ushort4*)(zb + (size_t)(p + NB) * DIM + lane * 4) = b;
    float ki = si * SCALE, kj = sj * SCALE;
    ushort4 a2, b2;
    a2.x = f2bf_rne(vi.x * ki); a2.y = f2bf_rne(vi.y * ki);
    a2.z = f2bf_rne(vi.z * ki); a2.w = f2bf_rne(vi.w * ki);
    b2.x = f2bf_rne(vj.x * kj); b2.y = f2bf_rne(vj.y * kj);
    b2.z = f2bf_rne(vj.z * kj); b2.w = f2bf_rne(vj.w * kj);
    *(ushort4*)(zb2 + (size_t)p * DIM + lane * 4) = a2;
    *(ushort4*)(zb2 + (size_t)(p + NB) * DIM + lane * 4) = b2;
    if (lane == 0) pd[p] = dij * si * sj;
}

// K2: triangular 128x128 tiles; row sums -> P[jb][ib*128+r], col sums ->
// P[ib][jb*128+c]. Every P slot written exactly once; zero atomics.
__global__ __launch_bounds__(256) void k_sim(const unsigned short* __restrict__ zb,
                                             const unsigned short* __restrict__ zb2,
                                             float* __restrict__ P) {
    __shared__ __attribute__((aligned(16))) short Bs[64 * LDS_STRIDE];
    __shared__ float cs[128];
    // decode triangular tile: ib in [0,32), jb in [ib,32)
    int rem = blockIdx.x, ib = 0;
    while (rem >= 32 - ib) { rem -= 32 - ib; ib++; }
    int jb = ib + rem;
    bool do_col = (jb > ib);

    int tid = threadIdx.x, wave = tid >> 6, lane = tid & 63;
    int m = lane & 15, q = lane >> 4;
    const short* zsB = (const short*)zb;
    const short* zsA = (const short*)zb2;
    int ibase = ib * 128 + wave * 32;
    int jtile0 = jb * 128;

    if (tid < 128) cs[tid] = 0.0f;

    // A fragments: A[m][k], m = lane&15, k = q*8 + kk (verified 16x16x32 layout)
    short8 A[2][8];
    #pragma unroll
    for (int tt = 0; tt < 2; tt++) {
        const short* arow = zsA + (size_t)(ibase + tt * 16 + m) * DIM + q * 8;
        #pragma unroll
        for (int kk = 0; kk < 8; kk++) A[tt][kk] = *(const short8*)(arow + kk * 32);
    }

    float rowacc[2][4] = {{0.f, 0.f, 0.f, 0.f}, {0.f, 0.f, 0.f, 0.f}};

    #pragma unroll
    for (int strip = 0; strip < 2; strip++) {
        int j0 = jtile0 + strip * 64;
        __syncthreads();
        #pragma unroll
        for (int c = 0; c < 8; c++) {
            int chunk = c * 256 + tid;          // 16B chunks
            int r = chunk >> 5, cc = chunk & 31;
            *(short8*)(&Bs[r * LDS_STRIDE + cc * 8]) =
                *(const short8*)(zsB + (size_t)(j0 + r) * DIM + cc * 8);
        }
        __syncthreads();

        #pragma unroll
        for (int jt = 0; jt < 4; jt++) {
            const short* brow = &Bs[(jt * 16 + m) * LDS_STRIDE + q * 8];
            float4v c0 = {0.f, 0.f, 0.f, 0.f};
            float4v c1 = {0.f, 0.f, 0.f, 0.f};
            #pragma unroll
            for (int kk = 0; kk < 8; kk++) {
                short8 b = *(const short8*)(brow + kk * 32);
                c0 = __builtin_amdgcn_mfma_f32_16x16x32_bf16(A[0][kk], b, c0, 0, 0, 0);
                c1 = __builtin_amdgcn_mfma_f32_16x16x32_bf16(A[1][kk], b, c1, 0, 0, 0);
            }
            float csum = 0.0f;
            #pragma unroll
            for (int r = 0; r < 4; r++) {
                float e0 = __builtin_exp2f(c0[r]);
                float e1 = __builtin_exp2f(c1[r]);
                rowacc[0][r] += e0; rowacc[1][r] += e1;
                csum += e0 + e1;
            }
            if (do_col) {
                csum += __shfl_xor(csum, 16);
                csum += __shfl_xor(csum, 32);
                if (lane < 16) atomicAdd(&cs[strip * 64 + jt * 16 + m], csum);
            }
        }
    }

    // row sums -> P[jb][ibase + ...] (unique slots, plain stores)
    #pragma unroll
    for (int tt = 0; tt < 2; tt++) {
        #pragma unroll
        for (int r = 0; r < 4; r++) {
            float s = rowacc[tt][r];
            s += __shfl_xor(s, 1);
            s += __shfl_xor(s, 2);
            s += __shfl_xor(s, 4);
            s += __shfl_xor(s, 8);
            if (m == 0) P[(size_t)jb * NROWS + ibase + tt * 16 + q * 4 + r] = s;
        }
    }
    if (do_col) {
        __syncthreads();
        if (tid < 128) P[(size_t)ib * NROWS + jtile0 + tid] = cs[tid];
    }
}

// K3: S[i] = sum_p P[p][i]; loss = mean( log(S-e^2) - 2*pd ). grid 16 x 256.
__global__ __launch_bounds__(256) void k_loss(const float* __restrict__ P,
                                              const float* __restrict__ pd,
                                              float* __restrict__ out) {
    __shared__ float red[4];
    int wave = threadIdx.x >> 6, lane = threadIdx.x & 63;
    int i = blockIdx.x * 256 + threadIdx.x;
    float s = 0.0f;
    #pragma unroll
    for (int p = 0; p < 32; p++) s += P[(size_t)p * NROWS + i];
    const float E2 = 7.38905609893065f;  // exp(sim_ii) = e^2
    float term = logf(s - E2) - TEMP_INV * pd[i & (NB - 1)];
    #pragma unroll
    for (int off = 32; off > 0; off >>= 1) term += __shfl_xor(term, off);
    if (lane == 0) red[wave] = term;
    __syncthreads();
    if (threadIdx.x == 0) {
        float t = (red[0] + red[1] + red[2] + red[3]) * (1.0f / NROWS);
        atomicAdd(out, t);
    }
}

extern "C" void kernel_launch(void* const* d_in, const int* in_sizes, int n_in,
                              void* d_out, int out_size, void* d_ws, size_t ws_size,
                              hipStream_t stream) {
    const float* zi = (const float*)d_in[0];
    const float* zj = (const float*)d_in[1];
    float* out = (float*)d_out;
    char* ws = (char*)d_ws;
    unsigned short* zb  = (unsigned short*)ws;                        // 2 MB bf16 normalized
    unsigned short* zb2 = (unsigned short*)(ws + 2 * 1024 * 1024);    // 2 MB bf16 * 2log2e
    float* P  = (float*)(ws + 4 * 1024 * 1024);                       // 512 KB partials [32][4096]
    float* pd = (float*)(ws + 4 * 1024 * 1024 + 512 * 1024);          // 8 KB pos dots

    hipLaunchKernelGGL(k_norm, dim3(512), dim3(256), 0, stream, zi, zj, zb, zb2, pd, out);
    hipLaunchKernelGGL(k_sim, dim3(NTILES), dim3(256), 0, stream, zb, zb2, P);
    hipLaunchKernelGGL(k_loss, dim3(16), dim3(256), 0, stream, P, pd, out);
}